// Round 5
// baseline (348.169 us; speedup 1.0000x reference)
//
#include <hip/hip_runtime.h>
#include <stdint.h>

typedef unsigned short u16;
typedef unsigned int u32;
typedef __attribute__((ext_vector_type(8))) short bf16x8;   // 8 bf16 = 4 VGPRs (MFMA A/B frag)
typedef __attribute__((ext_vector_type(8))) unsigned short u16x8;
typedef __attribute__((ext_vector_type(4))) float f32x4;
typedef __attribute__((ext_vector_type(4))) int i32x4;

__device__ __forceinline__ u16 f2bf(float f) {
  uint32_t u = __builtin_bit_cast(uint32_t, f);
  u += 0x7fffu + ((u >> 16) & 1u);   // RNE
  return (u16)(u >> 16);
}

// async global->LDS, 16B per lane; LDS dest must be wave-uniform base (+lane*16 implicit)
#define GLD16(g, l)                                                         \
  __builtin_amdgcn_global_load_lds(                                         \
      (const __attribute__((address_space(1))) void*)(g),                   \
      (__attribute__((address_space(3))) void*)(l), 16, 0, 0)

// ---------------- elementwise prep kernels (verified) ----------------

__global__ __launch_bounds__(256) void cvt_f32_bf16(const float* __restrict__ src,
                                                    u16* __restrict__ dst, int n8) {
  int t = blockIdx.x * 256 + threadIdx.x;
  if (t >= n8) return;
  f32x4 a = ((const f32x4*)src)[2 * t];
  f32x4 b = ((const f32x4*)src)[2 * t + 1];
  u16x8 o;
  o[0] = f2bf(a[0]); o[1] = f2bf(a[1]); o[2] = f2bf(a[2]); o[3] = f2bf(a[3]);
  o[4] = f2bf(b[0]); o[5] = f2bf(b[1]); o[6] = f2bf(b[2]); o[7] = f2bf(b[3]);
  ((u16x8*)dst)[t] = o;
}

__global__ __launch_bounds__(256) void bias_init(float* __restrict__ out,
                                                 const float* __restrict__ b,
                                                 int N, int n4) {
  int t = blockIdx.x * 256 + threadIdx.x;
  if (t >= n4) return;
  int idx = t * 4;
  int n = idx & (N - 1);          // N is a power of two (2048)
  *(f32x4*)(out + idx) = *(const f32x4*)(b + n);
}

// ------- NT GEMM with FUSED INT4 DEQUANT of B: C[M,N] = A[M,K] * dq(Q)[N,K]^T -------
// 128x128 tile, 4 waves 2x2, 4x4 MFMA 16x16x32 bf16 per wave, BK=64 (2 ksubs).
// A: bf16, staged via GLD16 (4/stage/wave), pre-swizzled global source chunk.
// B: int32 quant values, reg-staged (8x dwordx4/stage/wave) + per-row scale/zero
//    (2 loads) -> dequant to bf16 in regs -> 4x ds_write_b128 into the SAME
//    chunk^= (row&7) swizzled LDS layout the MFMA frag reads expect.
// Counted-vmcnt: each stage = exactly 14 vmem (4 GLD16 + 8 B + s + z); 2-deep,
// steady-state vmcnt(14); loads pinned in their window by the "memory" asm fences.
// Per BK-step: one barrier pair, lgkm(8)-split MFMA overlap (r3-verified shape).
template <bool RELU, bool OUT_BF16, bool ATOMIC>
__global__ __launch_bounds__(256, 2) void gemm_dq(const u16* __restrict__ A,
                                                  const int* __restrict__ Q,
                                                  const float* __restrict__ S,
                                                  const float* __restrict__ Z,
                                                  const float* __restrict__ bias,
                                                  void* __restrict__ Cout,
                                                  int N, int K, int kChunk) {
  __shared__ u16 As[2][128 * 64];   // 2 x 16KB
  __shared__ u16 Bs[2][128 * 64];   // 2 x 16KB  (total 64KB -> 2 blocks/CU)
  const int tid = threadIdx.x;
  const int wave = tid >> 6;
  const int lane = tid & 63;
  const int m0 = blockIdx.y << 7;
  const int n0 = blockIdx.x << 7;
  const int kStart = blockIdx.z * kChunk;

  // ---- A staging (GLD16, r3-verified): 8 rows x 128B per load ----
  const int srow = lane >> 3;
  const int schunk = (((lane & 7) ^ (srow & 7)) << 3);   // pre-swizzled source chunk
  const u16* Ab = A + (size_t)(m0 + 32 * wave + srow) * K + kStart + schunk;
  const size_t rs8 = (size_t)8 * K;

  // ---- B reg staging: lane -> (row br = lane>>1, half = lane&1 of the 64-wide k) ----
  const int br = lane >> 1;
  const int hf = lane & 1;
  const int brow = n0 + 32 * wave + br;
  const int* Qb = Q + (size_t)brow * K + kStart + hf * 32;
  const int nG = K >> 7;                                  // groups per row (GROUP=128)
  const float* Sb = S + (size_t)brow * nG + (kStart >> 7);
  const float* Zb = Z + (size_t)brow * nG + (kStart >> 7);

  // ---- MFMA frag read offsets (both A and B LDS hold: LDS(row,c)=global(row,c^(row&7))) ----
  const int wm = (wave >> 1) << 6;
  const int wn = (wave & 1) << 6;
  const int quad = lane >> 4;
  const int l15 = lane & 15;
  const int x7 = lane & 7;
  const int c0 = ((quad ^ x7) << 3);                      // ksub 0
  const int c1 = (((4 | quad) ^ x7) << 3);                // ksub 1

  const int ldsW = (32 * wave) * 64;
  const int nT = kChunk >> 6;                             // 32 (gemm1) / 16 (gemm2), even

  f32x4 acc[4][4];
#pragma unroll
  for (int i = 0; i < 4; i++)
#pragma unroll
    for (int j = 0; j < 4; j++) acc[i][j] = (f32x4){0.f, 0.f, 0.f, 0.f};

  i32x4 rA[8], rB[8];
  float scA, zpA, scB, zpB;

  // stage t_: 4 GLD16 (A -> As[bi_]) + 8 dwordx4 (B -> rb_) + s + z  == 14 vmem
#define ISSUE(bi_, t_, rb_, sc_, zp_)                                 \
  do {                                                                \
    const int ko_ = (t_) << 6;                                        \
    GLD16(Ab + ko_,           &As[bi_][ldsW]);                        \
    GLD16(Ab + ko_ + rs8,     &As[bi_][ldsW + 512]);                  \
    GLD16(Ab + ko_ + 2 * rs8, &As[bi_][ldsW + 1024]);                 \
    GLD16(Ab + ko_ + 3 * rs8, &As[bi_][ldsW + 1536]);                 \
    const i32x4* qp_ = (const i32x4*)(Qb + ko_);                      \
    _Pragma("unroll") for (int j = 0; j < 8; j++) rb_[j] = qp_[j];    \
    sc_ = Sb[(t_) >> 1];                                              \
    zp_ = Zb[(t_) >> 1];                                              \
  } while (0)

  // dequant 32 ints -> 32 bf16, write 4x b128 into swizzled slots of Bs[bi_]
#define CVTW(bi_, rb_, sc_, zp_)                                      \
  do {                                                                \
    u16* wp_ = &Bs[bi_][(32 * wave + br) * 64];                       \
    _Pragma("unroll") for (int c = 0; c < 4; c++) {                   \
      u16x8 o_;                                                       \
      _Pragma("unroll") for (int e = 0; e < 4; e++) {                 \
        o_[e]     = f2bf(((float)rb_[2 * c][e]     - (zp_)) * (sc_)); \
        o_[e + 4] = f2bf(((float)rb_[2 * c + 1][e] - (zp_)) * (sc_)); \
      }                                                               \
      const int slot_ = ((hf * 4 + c) ^ (br & 7));                    \
      *(u16x8*)(wp_ + slot_ * 8) = o_;                                \
    }                                                                 \
  } while (0)

  bf16x8 af0[4], bf0[4], af1[4], bf1[4];
#define LOADFRAGS(bi_)                                                          \
  do {                                                                          \
    _Pragma("unroll") for (int i = 0; i < 4; i++)                               \
        af0[i] = *(const bf16x8*)&As[bi_][(wm + i * 16 + l15) * 64 + c0];       \
    _Pragma("unroll") for (int j = 0; j < 4; j++)                               \
        bf0[j] = *(const bf16x8*)&Bs[bi_][(wn + j * 16 + l15) * 64 + c0];       \
    _Pragma("unroll") for (int i = 0; i < 4; i++)                               \
        af1[i] = *(const bf16x8*)&As[bi_][(wm + i * 16 + l15) * 64 + c1];       \
    _Pragma("unroll") for (int j = 0; j < 4; j++)                               \
        bf1[j] = *(const bf16x8*)&Bs[bi_][(wn + j * 16 + l15) * 64 + c1];       \
  } while (0)

#define MFMA_S0()                                                               \
  do {                                                                          \
    _Pragma("unroll") for (int i = 0; i < 4; i++)                               \
        _Pragma("unroll") for (int j = 0; j < 4; j++)                           \
            acc[i][j] = __builtin_amdgcn_mfma_f32_16x16x32_bf16(                \
                af0[i], bf0[j], acc[i][j], 0, 0, 0);                            \
  } while (0)

#define MFMA_S1()                                                               \
  do {                                                                          \
    _Pragma("unroll") for (int i = 0; i < 4; i++)                               \
        _Pragma("unroll") for (int j = 0; j < 4; j++)                           \
            acc[i][j] = __builtin_amdgcn_mfma_f32_16x16x32_bf16(                \
                af1[i], bf1[j], acc[i][j], 0, 0, 0);                            \
  } while (0)

  // ---- prologue: stage0 -> (As[0], rA); stage1 -> (As[1], rB); materialize B0 ----
  ISSUE(0, 0, rA, scA, zpA);
  ISSUE(1, 1, rB, scB, zpB);
  asm volatile("s_waitcnt vmcnt(14)" ::: "memory");   // stage0 fully landed
  CVTW(0, rA, scA, zpA);
  asm volatile("s_waitcnt lgkmcnt(0)" ::: "memory");
  __builtin_amdgcn_s_barrier();

  // ---- main loop, unrolled by 2 for static reg-set names (rule #20) ----
  for (int t = 0; t < nT; t += 2) {
    // ======== even iter (cur = buf0, stage t) ========
    LOADFRAGS(0);
    asm volatile("s_waitcnt lgkmcnt(8)" ::: "memory");
    __builtin_amdgcn_sched_barrier(0);
    MFMA_S0();
    asm volatile("s_waitcnt lgkmcnt(0)" ::: "memory");
    __builtin_amdgcn_sched_barrier(0);
    __builtin_amdgcn_s_barrier();            // all waves done reading buf0
    if (t + 2 < nT) ISSUE(0, t + 2, rA, scA, zpA);   // refill buf0's A + rA
    MFMA_S1();
    if (t + 2 < nT)
      asm volatile("s_waitcnt vmcnt(14)" ::: "memory");  // stage t+1 landed
    else
      asm volatile("s_waitcnt vmcnt(0)" ::: "memory");
    __builtin_amdgcn_sched_barrier(0);
    CVTW(1, rB, scB, zpB);                   // stage t+1 B -> buf1
    asm volatile("s_waitcnt lgkmcnt(0)" ::: "memory");
    __builtin_amdgcn_s_barrier();            // buf1 fully staged

    // ======== odd iter (cur = buf1, stage t+1) ========
    LOADFRAGS(1);
    asm volatile("s_waitcnt lgkmcnt(8)" ::: "memory");
    __builtin_amdgcn_sched_barrier(0);
    MFMA_S0();
    asm volatile("s_waitcnt lgkmcnt(0)" ::: "memory");
    __builtin_amdgcn_sched_barrier(0);
    if (t + 2 >= nT) {                       // stage t+1 == nT-1: last tile
      MFMA_S1();
      break;
    }
    __builtin_amdgcn_s_barrier();            // all waves done reading buf1
    if (t + 3 < nT) ISSUE(1, t + 3, rB, scB, zpB);   // refill buf1's A + rB
    MFMA_S1();
    if (t + 3 < nT)
      asm volatile("s_waitcnt vmcnt(14)" ::: "memory");  // stage t+2 landed
    else
      asm volatile("s_waitcnt vmcnt(0)" ::: "memory");
    __builtin_amdgcn_sched_barrier(0);
    CVTW(0, rA, scA, zpA);                   // stage t+2 B -> buf0
    asm volatile("s_waitcnt lgkmcnt(0)" ::: "memory");
    __builtin_amdgcn_s_barrier();            // buf0 fully staged
  }

#undef ISSUE
#undef CVTW
#undef LOADFRAGS
#undef MFMA_S0
#undef MFMA_S1

  // epilogue: C/D layout col=lane&15, row=quad*4+reg (verified m89/m91)
#pragma unroll
  for (int i = 0; i < 4; i++) {
#pragma unroll
    for (int j = 0; j < 4; j++) {
      const int col = n0 + wn + j * 16 + l15;
      float bv = 0.f;
      if (!ATOMIC) bv = bias[col];
#pragma unroll
      for (int r = 0; r < 4; r++) {
        const int row = m0 + wm + i * 16 + quad * 4 + r;
        float v = acc[i][j][r];
        if (ATOMIC) {
          atomicAdd((float*)Cout + (size_t)row * N + col, v);
        } else {
          v += bv;
          if (RELU) v = v > 0.f ? v : 0.f;
          if (OUT_BF16)
            ((u16*)Cout)[(size_t)row * N + col] = f2bf(v);
          else
            ((float*)Cout)[(size_t)row * N + col] = v;
        }
      }
    }
  }
}

// ---------------- launch ----------------

extern "C" void kernel_launch(void* const* d_in, const int* in_sizes, int n_in,
                              void* d_out, int out_size, void* d_ws, size_t ws_size,
                              hipStream_t stream) {
  const float* x  = (const float*)d_in[0];
  const int*   q1 = (const int*)d_in[1];
  const float* s1 = (const float*)d_in[2];
  const float* z1 = (const float*)d_in[3];
  const float* b1 = (const float*)d_in[4];
  const int*   q2 = (const int*)d_in[5];
  const float* s2 = (const float*)d_in[6];
  const float* z2 = (const float*)d_in[7];
  const float* b2 = (const float*)d_in[8];
  float* out = (float*)d_out;

  const int B = 512, D_IN = 2048, D_H = 8192, D_OUT = 2048;

  char* ws = (char*)d_ws;
  u16* xb = (u16*)(ws);                                  // 2 MB: x bf16 [512][2048]
  u16* hb = (u16*)(ws + (size_t)2 * 1024 * 1024);        // 8 MB: h bf16 [512][8192]

  // 1. x -> bf16
  cvt_f32_bf16<<<(B * D_IN / 8 + 255) / 256, 256, 0, stream>>>(x, xb, B * D_IN / 8);
  // 2. h = relu(x @ dq(q1)^T + b1), bf16 out; dequant fused into B-staging. nT=32.
  dim3 g1(D_H / 128, B / 128, 1);
  gemm_dq<true, true, false><<<g1, 256, 0, stream>>>(xb, q1, s1, z1, b1, hb,
                                                     D_H, D_IN, D_IN);
  // 3. out = b2 broadcast, then split-K=8 atomic: out += h @ dq(q2)^T. nT=16.
  bias_init<<<(B * D_OUT / 4 + 255) / 256, 256, 0, stream>>>(out, b2, D_OUT, B * D_OUT / 4);
  dim3 g2(D_OUT / 128, B / 128, 8);
  gemm_dq<false, false, true><<<g2, 256, 0, stream>>>(hb, q2, s2, z2, nullptr, out,
                                                      D_OUT, D_H, D_H / 8);
}

// Round 6
// 322.493 us; speedup vs baseline: 1.0796x; 1.0796x over previous
//
#include <hip/hip_runtime.h>
#include <stdint.h>

typedef unsigned short u16;
typedef __attribute__((ext_vector_type(8))) short bf16x8;   // 8 bf16 = 4 VGPRs (MFMA A/B frag)
typedef __attribute__((ext_vector_type(8))) unsigned short u16x8;
typedef __attribute__((ext_vector_type(4))) float f32x4;
typedef __attribute__((ext_vector_type(4))) int i32x4;

__device__ __forceinline__ u16 f2bf(float f) {
  uint32_t u = __builtin_bit_cast(uint32_t, f);
  u += 0x7fffu + ((u >> 16) & 1u);   // RNE
  return (u16)(u >> 16);
}

// async global->LDS, 16B per lane; LDS dest must be wave-uniform base (+lane*16 implicit)
#define GLD16(g, l)                                                         \
  __builtin_amdgcn_global_load_lds(                                         \
      (const __attribute__((address_space(1))) void*)(g),                   \
      (__attribute__((address_space(3))) void*)(l), 16, 0, 0)

// ---------------- elementwise prep kernels (r0/r3-verified) ----------------

__global__ __launch_bounds__(256) void cvt_f32_bf16(const float* __restrict__ src,
                                                    u16* __restrict__ dst, int n8) {
  int t = blockIdx.x * 256 + threadIdx.x;
  if (t >= n8) return;
  f32x4 a = ((const f32x4*)src)[2 * t];
  f32x4 b = ((const f32x4*)src)[2 * t + 1];
  u16x8 o;
  o[0] = f2bf(a[0]); o[1] = f2bf(a[1]); o[2] = f2bf(a[2]); o[3] = f2bf(a[3]);
  o[4] = f2bf(b[0]); o[5] = f2bf(b[1]); o[6] = f2bf(b[2]); o[7] = f2bf(b[3]);
  ((u16x8*)dst)[t] = o;
}

// q:[O][G][128] int32 (flat == row-major [O][I]), s/z:[O][G] -> w bf16 [O][I]
__global__ __launch_bounds__(256) void dequant_w(const int* __restrict__ q,
                                                 const float* __restrict__ s,
                                                 const float* __restrict__ z,
                                                 u16* __restrict__ w, int n8) {
  int t = blockIdx.x * 256 + threadIdx.x;
  if (t >= n8) return;
  int g = t >> 4;                 // 8 elems/thread, 128 elems/group -> 16 threads/group
  float sc = s[g];
  float zp = z[g];
  i32x4 a = ((const i32x4*)q)[2 * t];
  i32x4 b = ((const i32x4*)q)[2 * t + 1];
  u16x8 o;
  o[0] = f2bf(((float)a[0] - zp) * sc);
  o[1] = f2bf(((float)a[1] - zp) * sc);
  o[2] = f2bf(((float)a[2] - zp) * sc);
  o[3] = f2bf(((float)a[3] - zp) * sc);
  o[4] = f2bf(((float)b[0] - zp) * sc);
  o[5] = f2bf(((float)b[1] - zp) * sc);
  o[6] = f2bf(((float)b[2] - zp) * sc);
  o[7] = f2bf(((float)b[3] - zp) * sc);
  ((u16x8*)w)[t] = o;
}

__global__ __launch_bounds__(256) void bias_init(float* __restrict__ out,
                                                 const float* __restrict__ b,
                                                 int N, int n4) {
  int t = blockIdx.x * 256 + threadIdx.x;
  if (t >= n4) return;
  int idx = t * 4;
  int n = idx & (N - 1);          // N is a power of two (8192 / 2048)
  *(f32x4*)(out + idx) = *(const f32x4*)(b + n);
}

// hb = bf16(relu(h32)), 8 elems/thread
__global__ __launch_bounds__(256) void relu_cvt(const float* __restrict__ h32,
                                                u16* __restrict__ hb, int n8) {
  int t = blockIdx.x * 256 + threadIdx.x;
  if (t >= n8) return;
  f32x4 a = ((const f32x4*)h32)[2 * t];
  f32x4 b = ((const f32x4*)h32)[2 * t + 1];
  u16x8 o;
#pragma unroll
  for (int e = 0; e < 4; e++) {
    float va = a[e] > 0.f ? a[e] : 0.f;
    float vb = b[e] > 0.f ? b[e] : 0.f;
    o[e] = f2bf(va);
    o[e + 4] = f2bf(vb);
  }
  ((u16x8*)hb)[t] = o;
}

// ------- NT GEMM, 256x256 tile, atomic split-K: C[M,N] += A[M,K] * B[N,K]^T -------
// 8 waves (512 thr) in 2x4, each wave 128x64 via 8x4 MFMA 16x16x32 bf16, BK=32.
// Rationale (r0/r1/r3 post-mortem): all 128^2 variants plateau at 4.5-5.5 TB/s of
// tile fetch (268 MB/GEMM). 256^2 halves fetch to 134 MB (AI doubles); split-K
// keeps grid at 256 blocks = 1 block/CU (8 waves = 2/SIMD).
// Staging/swizzle/sync are the r1-verified forms verbatim:
//   - per wave: 2 GLD16 A + 2 GLD16 B per stage (wave stages its own 32 rows)
//   - swizzle LDS(row,c)=global(row, c^((row>>1)&3)), read cs=(quad^((l15>>1)&3))<<3
//     (0 bank conflicts measured in r1)
//   - 2-deep counted-vmcnt: steady vmcnt(4), tail vmcnt(4)/vmcnt(0); wait-then-barrier.
__global__ __launch_bounds__(512, 2) void gemm256_at(const u16* __restrict__ A,
                                                     const u16* __restrict__ Bm,
                                                     float* __restrict__ Cout,
                                                     int N, int K, int kChunk) {
  __shared__ u16 As[2][256 * 32];   // 2 x 16KB
  __shared__ u16 Bs[2][256 * 32];   // 2 x 16KB  (total 64KB -> 1 block/CU)
  const int tid = threadIdx.x;
  const int wave = tid >> 6;          // 0..7
  const int lane = tid & 63;
  const int m0 = blockIdx.y << 8;
  const int n0 = blockIdx.x << 8;
  const int kStart = blockIdx.z * kChunk;
  const int srow = lane >> 2;         // staging: 16 rows x 4 lanes*16B per GLD16
  const int scol = (((lane & 3) ^ ((lane >> 3) & 3)) << 3);   // pre-swizzled src chunk
  const int wm = (wave >> 2) << 7;    // 0 or 128
  const int wn = (wave & 3) << 6;     // 0,64,128,192
  const int quad = lane >> 4;
  const int l15 = lane & 15;
  const int cs = ((quad ^ ((l15 >> 1) & 3)) << 3);            // swizzled read offset

  const u16* Ab = A + (size_t)(m0 + 32 * wave + srow) * K + kStart + scol;
  const u16* Bb = Bm + (size_t)(n0 + 32 * wave + srow) * K + kStart + scol;
  const int ldsW = (32 * wave) * 32;  // u16 offset of this wave's 32-row staging region
  const size_t rowskip = (size_t)16 * K;
  const int nT = kChunk >> 5;         // 16 for both GEMMs here (>= 2 required)

  f32x4 acc[8][4];
#pragma unroll
  for (int i = 0; i < 8; i++)
#pragma unroll
    for (int j = 0; j < 4; j++) acc[i][j] = (f32x4){0.f, 0.f, 0.f, 0.f};

  // stage K-step t_ into buffer bi_ : exactly 4 GLD16 per wave (vmcnt counts on this)
#define STAGE(bi_, t_)                                    \
  do {                                                    \
    const int ko_ = (t_) << 5;                            \
    GLD16(Ab + ko_, &As[bi_][ldsW]);                      \
    GLD16(Ab + ko_ + rowskip, &As[bi_][ldsW + 512]);      \
    GLD16(Bb + ko_, &Bs[bi_][ldsW]);                      \
    GLD16(Bb + ko_ + rowskip, &Bs[bi_][ldsW + 512]);      \
  } while (0)

  bf16x8 af[8], bf[4];
#define LOADFRAGS(bi_)                                                        \
  do {                                                                        \
    _Pragma("unroll") for (int i = 0; i < 8; i++)                             \
        af[i] = *(const bf16x8*)&As[bi_][(wm + i * 16 + l15) * 32 + cs];      \
    _Pragma("unroll") for (int j = 0; j < 4; j++)                             \
        bf[j] = *(const bf16x8*)&Bs[bi_][(wn + j * 16 + l15) * 32 + cs];      \
  } while (0)

#define DOMFMA()                                                              \
  do {                                                                        \
    _Pragma("unroll") for (int i = 0; i < 8; i++)                             \
        _Pragma("unroll") for (int j = 0; j < 4; j++)                         \
            acc[i][j] = __builtin_amdgcn_mfma_f32_16x16x32_bf16(              \
                af[i], bf[j], acc[i][j], 0, 0, 0);                            \
  } while (0)

  // prologue: fill the 2-deep pipe (8 loads in flight per wave)
  STAGE(0, 0);
  STAGE(1, 1);

  // main loop: t in [0, nT-2)
  for (int t = 0; t < nT - 2; ++t) {
    // outstanding = stages {t, t+1} = 8; retire the oldest 4 (stage t)
    asm volatile("s_waitcnt vmcnt(4)" ::: "memory");
    __builtin_amdgcn_s_barrier();              // all waves' stage(t) visible in LDS
    LOADFRAGS(t & 1);                          // 12 ds_read_b128
    asm volatile("s_waitcnt lgkmcnt(0)" ::: "memory");   // frags landed in regs
    __builtin_amdgcn_sched_barrier(0);         // rule #18
    __builtin_amdgcn_s_barrier();              // all waves done reading buf
    STAGE(t & 1, t + 2);                       // overwrite with tile t+2
    DOMFMA();                                  // overlaps stage issue
  }
  // t = nT-2: outstanding {nT-2, nT-1} = 8; retire oldest 4; no further staging
  asm volatile("s_waitcnt vmcnt(4)" ::: "memory");
  __builtin_amdgcn_s_barrier();
  LOADFRAGS(nT & 1);                           // (nT-2)&1 == nT&1
  asm volatile("s_waitcnt lgkmcnt(0)" ::: "memory");
  __builtin_amdgcn_sched_barrier(0);
  DOMFMA();
  // t = nT-1: drain
  asm volatile("s_waitcnt vmcnt(0)" ::: "memory");
  __builtin_amdgcn_s_barrier();
  LOADFRAGS((nT - 1) & 1);
  asm volatile("s_waitcnt lgkmcnt(0)" ::: "memory");
  __builtin_amdgcn_sched_barrier(0);
  DOMFMA();

#undef STAGE
#undef LOADFRAGS
#undef DOMFMA

  // epilogue: C/D layout col=lane&15, row=quad*4+reg (verified m89/m91); atomic split-K
#pragma unroll
  for (int i = 0; i < 8; i++) {
#pragma unroll
    for (int j = 0; j < 4; j++) {
      const int col = n0 + wn + j * 16 + l15;
#pragma unroll
      for (int r = 0; r < 4; r++) {
        const int row = m0 + wm + i * 16 + quad * 4 + r;
        atomicAdd(Cout + (size_t)row * N + col, acc[i][j][r]);
      }
    }
  }
}

// ---------------- launch ----------------

extern "C" void kernel_launch(void* const* d_in, const int* in_sizes, int n_in,
                              void* d_out, int out_size, void* d_ws, size_t ws_size,
                              hipStream_t stream) {
  const float* x  = (const float*)d_in[0];
  const int*   q1 = (const int*)d_in[1];
  const float* s1 = (const float*)d_in[2];
  const float* z1 = (const float*)d_in[3];
  const float* b1 = (const float*)d_in[4];
  const int*   q2 = (const int*)d_in[5];
  const float* s2 = (const float*)d_in[6];
  const float* z2 = (const float*)d_in[7];
  const float* b2 = (const float*)d_in[8];
  float* out = (float*)d_out;

  const int B = 512, D_IN = 2048, D_H = 8192, D_OUT = 2048;

  // workspace (peak 58 MB): w2b reuses w1b's slot after gemm1 is done with it.
  char* ws = (char*)d_ws;
  u16*   xb  = (u16*)(ws);                                  //  0- 2 MB: x bf16 [512][2048]
  u16*   w1b = (u16*)(ws + (size_t)2 * 1024 * 1024);        //  2-34 MB: w1 bf16 [8192][2048]
  u16*   w2b = w1b;                                         //  2-34 MB: w2 bf16 [2048][8192] (after gemm1)
  float* h32 = (float*)(ws + (size_t)34 * 1024 * 1024);     // 34-50 MB: h f32 [512][8192]
  u16*   hb  = (u16*)(ws + (size_t)50 * 1024 * 1024);       // 50-58 MB: h bf16 [512][8192]

  // 1. x -> bf16
  cvt_f32_bf16<<<(B * D_IN / 8 + 255) / 256, 256, 0, stream>>>(x, xb, B * D_IN / 8);
  // 2. dequant w1 -> bf16
  dequant_w<<<(D_H * D_IN / 8 + 255) / 256, 256, 0, stream>>>(q1, s1, z1, w1b, D_H * D_IN / 8);
  // 3. h32 = b1 broadcast, then split-K=4 atomic: h32 += x @ w1^T. grid 256 = 1/CU.
  bias_init<<<(B * D_H / 4 + 255) / 256, 256, 0, stream>>>(h32, b1, D_H, B * D_H / 4);
  {
    dim3 g1(D_H / 256, B / 256, 4);           // (32, 2, 4) = 256 blocks, kChunk 512, nT 16
    gemm256_at<<<g1, 512, 0, stream>>>(xb, w1b, h32, D_H, D_IN, D_IN / 4);
  }
  // 4. hb = bf16(relu(h32))
  relu_cvt<<<(B * D_H / 8 + 255) / 256, 256, 0, stream>>>(h32, hb, B * D_H / 8);
  // 5. dequant w2 -> bf16 (into w1b's slot; w1b dead after gemm1)
  dequant_w<<<(D_OUT * D_H / 8 + 255) / 256, 256, 0, stream>>>(q2, s2, z2, w2b, D_OUT * D_H / 8);
  // 6. out = b2 broadcast, then split-K=16 atomic: out += h @ w2^T. grid 256 = 1/CU.
  bias_init<<<(B * D_OUT / 4 + 255) / 256, 256, 0, stream>>>(out, b2, D_OUT, B * D_OUT / 4);
  {
    dim3 g2(D_OUT / 256, B / 256, 16);        // (8, 2, 16) = 256 blocks, kChunk 512, nT 16
    gemm256_at<<<g2, 512, 0, stream>>>(hb, w2b, out, D_OUT, D_H, D_H / 16);
  }
}

// Round 7
// 269.459 us; speedup vs baseline: 1.2921x; 1.1968x over previous
//
#include <hip/hip_runtime.h>
#include <stdint.h>

typedef unsigned short u16;
typedef __attribute__((ext_vector_type(8))) short bf16x8;   // 8 bf16 = 4 VGPRs (MFMA A/B frag)
typedef __attribute__((ext_vector_type(8))) unsigned short u16x8;
typedef __attribute__((ext_vector_type(4))) float f32x4;
typedef __attribute__((ext_vector_type(4))) int i32x4;

__device__ __forceinline__ u16 f2bf(float f) {
  uint32_t u = __builtin_bit_cast(uint32_t, f);
  u += 0x7fffu + ((u >> 16) & 1u);   // RNE
  return (u16)(u >> 16);
}

// async global->LDS, 16B per lane; LDS dest must be wave-uniform base (+lane*16 implicit)
#define GLD16(g, l)                                                         \
  __builtin_amdgcn_global_load_lds(                                         \
      (const __attribute__((address_space(1))) void*)(g),                   \
      (__attribute__((address_space(3))) void*)(l), 16, 0, 0)

// ---------------- elementwise prep kernels (r3-verified) ----------------

__global__ __launch_bounds__(256) void cvt_f32_bf16(const float* __restrict__ src,
                                                    u16* __restrict__ dst, int n8) {
  int t = blockIdx.x * 256 + threadIdx.x;
  if (t >= n8) return;
  f32x4 a = ((const f32x4*)src)[2 * t];
  f32x4 b = ((const f32x4*)src)[2 * t + 1];
  u16x8 o;
  o[0] = f2bf(a[0]); o[1] = f2bf(a[1]); o[2] = f2bf(a[2]); o[3] = f2bf(a[3]);
  o[4] = f2bf(b[0]); o[5] = f2bf(b[1]); o[6] = f2bf(b[2]); o[7] = f2bf(b[3]);
  ((u16x8*)dst)[t] = o;
}

// q:[O][G][128] int32 (flat == row-major [O][I]), s/z:[O][G] -> w bf16 [O][I]
// blockIdx.z selects tensor {0: w1, 1: w2}; both are 16.78M elements here.
__global__ __launch_bounds__(256) void dequant_w2x(const int* __restrict__ qa,
                                                   const float* __restrict__ sa,
                                                   const float* __restrict__ za,
                                                   u16* __restrict__ wa,
                                                   const int* __restrict__ qb,
                                                   const float* __restrict__ sb,
                                                   const float* __restrict__ zb,
                                                   u16* __restrict__ wb, int n8) {
  int t = blockIdx.x * 256 + threadIdx.x;
  if (t >= n8) return;
  const int* q = blockIdx.z ? qb : qa;
  const float* s = blockIdx.z ? sb : sa;
  const float* z = blockIdx.z ? zb : za;
  u16* w = blockIdx.z ? wb : wa;
  int g = t >> 4;                 // 8 elems/thread, 128 elems/group -> 16 threads/group
  float sc = s[g];
  float zp = z[g];
  i32x4 a = ((const i32x4*)q)[2 * t];
  i32x4 b = ((const i32x4*)q)[2 * t + 1];
  u16x8 o;
  o[0] = f2bf(((float)a[0] - zp) * sc);
  o[1] = f2bf(((float)a[1] - zp) * sc);
  o[2] = f2bf(((float)a[2] - zp) * sc);
  o[3] = f2bf(((float)a[3] - zp) * sc);
  o[4] = f2bf(((float)b[0] - zp) * sc);
  o[5] = f2bf(((float)b[1] - zp) * sc);
  o[6] = f2bf(((float)b[2] - zp) * sc);
  o[7] = f2bf(((float)b[3] - zp) * sc);
  ((u16x8*)w)[t] = o;
}

__global__ __launch_bounds__(256) void bias_init(float* __restrict__ out,
                                                 const float* __restrict__ b,
                                                 int N, int n4) {
  int t = blockIdx.x * 256 + threadIdx.x;
  if (t >= n4) return;
  int idx = t * 4;
  int n = idx & (N - 1);          // N is a power of two (2048)
  *(f32x4*)(out + idx) = *(const f32x4*)(b + n);
}

// ---------------- NT GEMM: C[M,N] = A[M,K] * B[N,K]^T (+bias, relu) ----------------
// BM=128, BN=32*NJ (NJ=4 -> 128x128, NJ=2 -> 128x64). 4 waves 2x2, each wave
// 64 x 16*NJ via 4xNJ MFMA 16x16x32 bf16, BK=32.
// r1-verified staging/swizzle: row = 64B; GLD16 covers 16 rows; pre-swizzled
// global source chunk scol = ((l&3)^((l>>3)&3))<<3; read cs = (quad^((l15>>1)&3))<<3
// (0 bank conflicts measured r1/r3/r6).
// r6-verified 2-deep counted-vmcnt sync: steady vmcnt(VM), tails vmcnt(VM)/vmcnt(0);
// VM = GLD16s per stage per wave = 2 (A) + NJ/2 (B).
// Occupancy rationale (r0/r1/r3/r6 post-mortem): all pipes idle, latency-bound at
// 1-2 blocks/CU; lever = more concurrent blocks. NJ=2: gemm1 at 512 blocks with
// fused epilogue. NJ=4 split-16: gemm2 at 1024 blocks (~3/CU; LDS 32KB).
template <int NJ, bool RELU, bool OUT_BF16, bool ATOMIC>
__global__ __launch_bounds__(256) void gemm_bt(const u16* __restrict__ A,
                                               const u16* __restrict__ Bm,
                                               const float* __restrict__ bias,
                                               void* __restrict__ Cout,
                                               int N, int K, int kChunk) {
  __shared__ u16 As[2][128 * 32];        // 2 x 8KB
  __shared__ u16 Bs[2][32 * NJ * 32];    // 2 x 2KB*NJ  (NJ=4: 32KB total; NJ=2: 24KB)
  const int tid = threadIdx.x;
  const int wave = tid >> 6;
  const int lane = tid & 63;
  const int m0 = blockIdx.y << 7;
  const int n0 = blockIdx.x * (32 * NJ);
  const int kStart = blockIdx.z * kChunk;
  const int srow = lane >> 2;            // 16 rows x 4 lanes*16B = 1KB per GLD16
  const int scol = (((lane & 3) ^ ((lane >> 3) & 3)) << 3);   // pre-swizzled src chunk
  const int wm = (wave >> 1) << 6;
  const int wn = (wave & 1) * (16 * NJ);
  const int quad = lane >> 4;
  const int l15 = lane & 15;
  const int cs = ((quad ^ ((l15 >> 1) & 3)) << 3);            // swizzled read offset

  const u16* Ab = A + (size_t)(m0 + 32 * wave + srow) * K + kStart + scol;
  const u16* Bb = Bm + (size_t)(n0 + (8 * NJ) * wave + srow) * K + kStart + scol;
  const int ldsA = (32 * wave) * 32;     // wave's 32-row A staging region (u16 offset)
  const int ldsB = ((8 * NJ) * wave) * 32;   // wave's 8*NJ-row B staging region
  const size_t rowskip = (size_t)16 * K;
  const int nT = kChunk >> 5;            // #BK=32 steps (>= 2)
  constexpr int VM = 2 + NJ / 2;         // GLD16s per stage per wave

  f32x4 acc[4][NJ];
#pragma unroll
  for (int i = 0; i < 4; i++)
#pragma unroll
    for (int j = 0; j < NJ; j++) acc[i][j] = (f32x4){0.f, 0.f, 0.f, 0.f};

  // stage K-step t_ into buffer bi_ : exactly VM GLD16 per wave (vmcnt counts on this)
#define STAGE(bi_, t_)                                        \
  do {                                                        \
    const int ko_ = (t_) << 5;                                \
    GLD16(Ab + ko_, &As[bi_][ldsA]);                          \
    GLD16(Ab + ko_ + rowskip, &As[bi_][ldsA + 512]);          \
    GLD16(Bb + ko_, &Bs[bi_][ldsB]);                          \
    if (NJ == 4) GLD16(Bb + ko_ + rowskip, &Bs[bi_][ldsB + 512]); \
  } while (0)

  bf16x8 af[4], bf[NJ];
#define LOADFRAGS(bi_)                                                        \
  do {                                                                        \
    _Pragma("unroll") for (int i = 0; i < 4; i++)                             \
        af[i] = *(const bf16x8*)&As[bi_][(wm + i * 16 + l15) * 32 + cs];      \
    _Pragma("unroll") for (int j = 0; j < NJ; j++)                            \
        bf[j] = *(const bf16x8*)&Bs[bi_][(wn + j * 16 + l15) * 32 + cs];      \
  } while (0)

#define DOMFMA()                                                              \
  do {                                                                        \
    _Pragma("unroll") for (int i = 0; i < 4; i++)                             \
        _Pragma("unroll") for (int j = 0; j < NJ; j++)                        \
            acc[i][j] = __builtin_amdgcn_mfma_f32_16x16x32_bf16(              \
                af[i], bf[j], acc[i][j], 0, 0, 0);                            \
  } while (0)

  // prologue: fill the 2-deep pipe (2*VM loads in flight per wave)
  STAGE(0, 0);
  STAGE(1, 1);

  // main loop: t in [0, nT-2)
  for (int t = 0; t < nT - 2; ++t) {
    // outstanding = stages {t, t+1} = 2*VM; retire the oldest VM (stage t)
    asm volatile("s_waitcnt vmcnt(%0)" ::"i"(VM) : "memory");
    __builtin_amdgcn_s_barrier();              // all waves' stage(t) visible in LDS
    LOADFRAGS(t & 1);
    asm volatile("s_waitcnt lgkmcnt(0)" ::: "memory");   // frags landed in regs
    __builtin_amdgcn_sched_barrier(0);         // rule #18
    __builtin_amdgcn_s_barrier();              // all waves done reading buf
    STAGE(t & 1, t + 2);                       // overwrite with tile t+2
    DOMFMA();                                  // overlaps stage issue
  }
  // t = nT-2: outstanding {nT-2, nT-1} = 2*VM; retire oldest VM; no further staging
  asm volatile("s_waitcnt vmcnt(%0)" ::"i"(VM) : "memory");
  __builtin_amdgcn_s_barrier();
  LOADFRAGS((nT - 2) & 1);
  asm volatile("s_waitcnt lgkmcnt(0)" ::: "memory");
  __builtin_amdgcn_sched_barrier(0);
  DOMFMA();
  // t = nT-1: drain
  asm volatile("s_waitcnt vmcnt(0)" ::: "memory");
  __builtin_amdgcn_s_barrier();
  LOADFRAGS((nT - 1) & 1);
  asm volatile("s_waitcnt lgkmcnt(0)" ::: "memory");
  __builtin_amdgcn_sched_barrier(0);
  DOMFMA();

#undef STAGE
#undef LOADFRAGS
#undef DOMFMA

  // epilogue: C/D layout col=lane&15, row=quad*4+reg (verified m89/m91)
#pragma unroll
  for (int i = 0; i < 4; i++) {
#pragma unroll
    for (int j = 0; j < NJ; j++) {
      const int col = n0 + wn + j * 16 + l15;
      float bv = 0.f;
      if (!ATOMIC) bv = bias[col];
#pragma unroll
      for (int r = 0; r < 4; r++) {
        const int row = m0 + wm + i * 16 + quad * 4 + r;
        float v = acc[i][j][r];
        if (ATOMIC) {
          atomicAdd((float*)Cout + (size_t)row * N + col, v);
        } else {
          v += bv;
          if (RELU) v = v > 0.f ? v : 0.f;
          if (OUT_BF16)
            ((u16*)Cout)[(size_t)row * N + col] = f2bf(v);
          else
            ((float*)Cout)[(size_t)row * N + col] = v;
        }
      }
    }
  }
}

// ---------------- launch ----------------

extern "C" void kernel_launch(void* const* d_in, const int* in_sizes, int n_in,
                              void* d_out, int out_size, void* d_ws, size_t ws_size,
                              hipStream_t stream) {
  const float* x  = (const float*)d_in[0];
  const int*   q1 = (const int*)d_in[1];
  const float* s1 = (const float*)d_in[2];
  const float* z1 = (const float*)d_in[3];
  const float* b1 = (const float*)d_in[4];
  const int*   q2 = (const int*)d_in[5];
  const float* s2 = (const float*)d_in[6];
  const float* z2 = (const float*)d_in[7];
  const float* b2 = (const float*)d_in[8];
  float* out = (float*)d_out;

  const int B = 512, D_IN = 2048, D_H = 8192, D_OUT = 2048;

  char* ws = (char*)d_ws;
  u16* xb  = (u16*)(ws);                                   //  2 MB: x bf16 [512][2048]
  u16* w1b = (u16*)(ws + (size_t)2 * 1024 * 1024);         // 32 MB: w1 bf16 [8192][2048]
  u16* hb  = (u16*)(ws + (size_t)34 * 1024 * 1024);        //  8 MB: h bf16 [512][8192]
  u16* w2b = (u16*)(ws + (size_t)42 * 1024 * 1024);        // 32 MB: w2 bf16 [2048][8192]

  // 1. x -> bf16
  cvt_f32_bf16<<<(B * D_IN / 8 + 255) / 256, 256, 0, stream>>>(x, xb, B * D_IN / 8);
  // 2. dequant both weights -> bf16 (one launch; both tensors are 16.78M elems)
  {
    const int n8 = D_H * D_IN / 8;            // == D_OUT * D_H / 8
    dim3 gd((n8 + 255) / 256, 1, 2);
    dequant_w2x<<<gd, 256, 0, stream>>>(q1, s1, z1, w1b, q2, s2, z2, w2b, n8);
  }
  // 3. h = relu(x @ w1^T + b1), bf16 out, fused epilogue.
  //    BN=64 tiles -> grid (128,4) = 512 blocks (2+/CU). nT = 64.
  {
    dim3 g1(D_H / 64, B / 128, 1);
    gemm_bt<2, true, true, false><<<g1, 256, 0, stream>>>(xb, w1b, b1, hb,
                                                          D_H, D_IN, D_IN);
  }
  // 4. out = b2 broadcast, then split-K=16 atomic: out += h @ w2^T.
  //    128x128 tiles -> grid (16,4,16) = 1024 blocks (~3/CU). nT = 16.
  bias_init<<<(B * D_OUT / 4 + 255) / 256, 256, 0, stream>>>(out, b2, D_OUT, B * D_OUT / 4);
  {
    dim3 g2(D_OUT / 128, B / 128, 16);
    gemm_bt<4, false, false, true><<<g2, 256, 0, stream>>>(hb, w2b, nullptr, out,
                                                           D_OUT, D_H, D_H / 16);
  }
}